// Round 15
// baseline (203.722 us; speedup 1.0000x reference)
//
#include <hip/hip_runtime.h>

#define NNODES 32768
#define NEDGES 524288
#define KCL 64
#define CPG 16

typedef _Float16 half8v __attribute__((ext_vector_type(8)));
typedef _Float16 half4v __attribute__((ext_vector_type(4)));
typedef float floatx4 __attribute__((ext_vector_type(4)));
typedef unsigned short ushort4v __attribute__((ext_vector_type(4)));

#define WT1_OFF   0
#define WT2_OFF   16384
#define WTA1_OFF  32768
#define WTA2_OFF  49152
#define WTO_OFF   57344
#define WT_TOTAL  73728

__device__ __forceinline__ float wave_sum(float v) {
#pragma unroll
  for (int off = 32; off > 0; off >>= 1) v += __shfl_xor(v, off, 64);
  return v;
}

// ---- fused: [0..127] histogram+ranks+weight prep ; [128..383] mgemm1 (x @ W1, UNSCALED fp16 out) ----
__global__ __launch_bounds__(256) void histmm_kernel(const int* __restrict__ src, const int* __restrict__ dst,
                                                     int* __restrict__ pIn, unsigned short* __restrict__ rank16,
                                                     const float* __restrict__ W1, const float* __restrict__ W2,
                                                     const float* __restrict__ Wa1, const float* __restrict__ Wa2,
                                                     const float* __restrict__ Wo, _Float16* __restrict__ wt16,
                                                     const float* __restrict__ x, _Float16* __restrict__ h16A) {
  __shared__ _Float16 WT[128][136];
  const int t = threadIdx.x;
  if (blockIdx.x < 128) {
    int* hIn = (int*)&WT[0][0];
    const int g = blockIdx.x & 7;
    const int chunk = blockIdx.x >> 3;
    const int ebase = (g << 16) + (chunk << 12);
    const int nbase = g << 12;
    for (int i = t; i < 4096; i += 256) hIn[i] = 0;
    __syncthreads();
    {
      int tg = blockIdx.x * 256 + t;
#pragma unroll
      for (int i = 0; i < 3; i++) {
        int id = tg + i * 32768;
        if (id < WT_TOTAL) {
          const float* W; int base, BN;
          if (id < 16384)      { W = W1;  base = WT1_OFF;  BN = 128; }
          else if (id < 32768) { W = W2;  base = WT2_OFF;  BN = 128; }
          else if (id < 49152) { W = Wa1; base = WTA1_OFF; BN = 128; }
          else if (id < 57344) { W = Wa2; base = WTA2_OFF; BN = 64; }
          else                 { W = Wo;  base = WTO_OFF;  BN = 128; }
          int m = id - base;
          int k = m / BN, n = m % BN;
          wt16[base + n * 128 + k] = (_Float16)W[m];
        }
      }
    }
    const int4* dst4 = reinterpret_cast<const int4*>(dst + ebase);
    ushort4v* rank4 = reinterpret_cast<ushort4v*>(rank16) + ((size_t)ebase >> 2);
#pragma unroll
    for (int i = 0; i < 4; ++i) {
      int4 d = dst4[i * 256 + t];
      ushort4v r;
      r[0] = (unsigned short)atomicAdd(&hIn[d.x - nbase], 1);
      r[1] = (unsigned short)atomicAdd(&hIn[d.y - nbase], 1);
      r[2] = (unsigned short)atomicAdd(&hIn[d.z - nbase], 1);
      r[3] = (unsigned short)atomicAdd(&hIn[d.w - nbase], 1);
      rank4[i * 256 + t] = r;
    }
    __syncthreads();
    int* dIn = pIn + ((size_t)(g * CPG + chunk) << 12);
    for (int i = t; i < 4096; i += 256) dIn[i] = hIn[i];
  } else {
    const int bid = blockIdx.x - 128;
    const int lane = t & 63;
    const int quad = lane >> 4, l16 = lane & 15;
    const long rowbase = (long)(bid & 7) * 4096 + (long)(bid >> 3) * 128 + (t >> 6) * 32;
    half8v af[2][4];
#pragma unroll
    for (int rt = 0; rt < 2; rt++)
#pragma unroll
      for (int kt = 0; kt < 4; kt++) {
        const float* p = x + (rowbase + rt * 16 + l16) * 128 + kt * 32 + quad * 8;
        float4 p0 = *reinterpret_cast<const float4*>(p);
        float4 p1 = *reinterpret_cast<const float4*>(p + 4);
        half8v h = {(_Float16)p0.x, (_Float16)p0.y, (_Float16)p0.z, (_Float16)p0.w,
                    (_Float16)p1.x, (_Float16)p1.y, (_Float16)p1.z, (_Float16)p1.w};
        af[rt][kt] = h;
      }
#pragma unroll
    for (int i = 0; i < 16; i++) {
      int idx = i * 256 + t;
      int k = idx >> 5, n4 = (idx & 31) * 4;
      float4 w = *reinterpret_cast<const float4*>(W1 + k * 128 + n4);
      WT[n4 + 0][k] = (_Float16)w.x;
      WT[n4 + 1][k] = (_Float16)w.y;
      WT[n4 + 2][k] = (_Float16)w.z;
      WT[n4 + 3][k] = (_Float16)w.w;
    }
    __syncthreads();
    floatx4 acc[2][8];
#pragma unroll
    for (int rt = 0; rt < 2; rt++)
#pragma unroll
      for (int ct = 0; ct < 8; ct++) acc[rt][ct] = {0.f, 0.f, 0.f, 0.f};
#pragma unroll
    for (int kt = 0; kt < 4; kt++) {
      half8v bf[8];
#pragma unroll
      for (int ct = 0; ct < 8; ct++)
        bf[ct] = *reinterpret_cast<const half8v*>(&WT[ct * 16 + l16][kt * 32 + quad * 8]);
#pragma unroll
      for (int rt = 0; rt < 2; rt++)
#pragma unroll
        for (int ct = 0; ct < 8; ct++)
          acc[rt][ct] = __builtin_amdgcn_mfma_f32_16x16x32_f16(af[rt][kt], bf[ct], acc[rt][ct], 0, 0, 0);
    }
#pragma unroll
    for (int rt = 0; rt < 2; rt++) {
#pragma unroll
      for (int r = 0; r < 4; r++) {
        long row = rowbase + rt * 16 + quad * 4 + r;
#pragma unroll
        for (int ct = 0; ct < 8; ct++)
          h16A[row * 128 + ct * 16 + l16] = (_Float16)acc[rt][ct][r];  // unscaled
      }
    }
  }
}

// ---------------- per-graph scan: offs, dis, per-chunk cursor bases ----------------
__global__ __launch_bounds__(1024) void scan2_kernel(const int* __restrict__ pIn, int* __restrict__ offs,
                                                     int* __restrict__ cbase, float* __restrict__ dis) {
  __shared__ int part[1024];
  const int t = threadIdx.x;
  const int g = blockIdx.x;
  int tot[4];
  int s = 0;
#pragma unroll
  for (int j = 0; j < 4; ++j) {
    int l = t * 4 + j;
    int cnt = 0;
#pragma unroll
    for (int c = 0; c < CPG; ++c) cnt += pIn[(((size_t)(g * CPG + c)) << 12) + l];
    tot[j] = cnt;
    s += cnt;
  }
  part[t] = s;
  __syncthreads();
  for (int off = 1; off < 1024; off <<= 1) {
    int add = (t >= off) ? part[t - off] : 0;
    __syncthreads();
    part[t] += add;
    __syncthreads();
  }
  int run = (g << 16) + ((t == 0) ? 0 : part[t - 1]);
#pragma unroll
  for (int j = 0; j < 4; ++j) {
    int l = t * 4 + j;
    int n = (g << 12) + l;
    offs[n] = run;
    dis[n] = rsqrtf((float)tot[j] + 1.0f);
    int running = run;
#pragma unroll
    for (int c = 0; c < CPG; ++c) {
      size_t idx = (((size_t)(g * CPG + c)) << 12) + l;
      cbase[idx] = running;
      running += pIn[idx];
    }
    run += tot[j];
  }
  if (g == 0 && t == 0) offs[NNODES] = NEDGES;
}

// ---------------- scatter (atomic-free via ranks) + h16A row-rescale by dis ----------------
__global__ __launch_bounds__(256) void scatter3_kernel(const int* __restrict__ src, const int* __restrict__ dst,
                                                       const unsigned short* __restrict__ rank16,
                                                       const int* __restrict__ cbase, int* __restrict__ ssrc,
                                                       const float* __restrict__ dis, _Float16* __restrict__ h16A) {
  const int t = threadIdx.x;
  const int g = blockIdx.x & 7;
  const int chunk = blockIdx.x >> 3;
  const int ebase = (g << 16) + (chunk << 12);
  const int nbase = g << 12;
  const int* cb = cbase + ((size_t)(g * CPG + chunk) << 12);
  const int4* dst4 = reinterpret_cast<const int4*>(dst + ebase);
  const int4* src4 = reinterpret_cast<const int4*>(src + ebase);
  const ushort4v* rank4 = reinterpret_cast<const ushort4v*>(rank16) + ((size_t)ebase >> 2);
#pragma unroll
  for (int i = 0; i < 4; ++i) {
    int4 d = dst4[i * 256 + t];
    int4 s = src4[i * 256 + t];
    ushort4v r = rank4[i * 256 + t];
    ssrc[cb[d.x - nbase] + r[0]] = s.x;
    ssrc[cb[d.y - nbase] + r[1]] = s.y;
    ssrc[cb[d.z - nbase] + r[2]] = s.z;
    ssrc[cb[d.w - nbase] + r[3]] = s.w;
  }
  // rescale this block's 256-node slice of h16A by dis[row] (rows nbase + chunk*256 ..)
  const int lane = t & 63;
  const int w = t >> 6;
#pragma unroll
  for (int i = 0; i < 4; ++i) {
    int row = nbase + (chunk << 8) + (i * 4 + w) * 16 + (lane >> 2);
    int c8 = (lane & 3) * 32 + 0;
    float sc = dis[row];
#pragma unroll
    for (int seg = 0; seg < 4; ++seg) {
      half8v v = *reinterpret_cast<half8v*>(&h16A[(size_t)row * 128 + c8 + seg * 8]);
#pragma unroll
      for (int j = 0; j < 8; j++) v[j] = (_Float16)((float)v[j] * sc);
      *reinterpret_cast<half8v*>(&h16A[(size_t)row * 128 + c8 + seg * 8]) = v;
    }
  }
}

// ---------------- MFMA fp16 GEMM ----------------
template <int ACT, int BIAS, int SCALE, int AFP32>
__global__ __launch_bounds__(256) void mgemm_kernel(const void* __restrict__ Ain, const _Float16* __restrict__ WT16,
                                                    const float* __restrict__ bias, const float* __restrict__ rowscale,
                                                    _Float16* __restrict__ Cout) {
  __shared__ _Float16 WT[128][136];
  const int t = threadIdx.x;
  const int lane = t & 63;
  const int quad = lane >> 4, l16 = lane & 15;
  const long rowbase = (long)(blockIdx.x & 7) * 4096 + (long)(blockIdx.x >> 3) * 128 + (t >> 6) * 32;
  half8v af[2][4];
#pragma unroll
  for (int rt = 0; rt < 2; rt++)
#pragma unroll
    for (int kt = 0; kt < 4; kt++) {
      if (AFP32) {
        const float* A32 = (const float*)Ain;
        const float* p = A32 + (rowbase + rt * 16 + l16) * 128 + kt * 32 + quad * 8;
        float4 p0 = *reinterpret_cast<const float4*>(p);
        float4 p1 = *reinterpret_cast<const float4*>(p + 4);
        half8v h = {(_Float16)p0.x, (_Float16)p0.y, (_Float16)p0.z, (_Float16)p0.w,
                    (_Float16)p1.x, (_Float16)p1.y, (_Float16)p1.z, (_Float16)p1.w};
        af[rt][kt] = h;
      } else {
        const _Float16* A16 = (const _Float16*)Ain;
        af[rt][kt] = *reinterpret_cast<const half8v*>(A16 + (rowbase + rt * 16 + l16) * 128 + kt * 32 + quad * 8);
      }
    }
#pragma unroll
  for (int i = 0; i < 8; i++) {
    int idx = i * 256 + t;
    int n = idx >> 4, k8 = (idx & 15) << 3;
    *reinterpret_cast<half8v*>(&WT[n][k8]) = *reinterpret_cast<const half8v*>(&WT16[n * 128 + k8]);
  }
  __syncthreads();
  floatx4 acc[2][8];
#pragma unroll
  for (int rt = 0; rt < 2; rt++)
#pragma unroll
    for (int ct = 0; ct < 8; ct++) acc[rt][ct] = {0.f, 0.f, 0.f, 0.f};
#pragma unroll
  for (int kt = 0; kt < 4; kt++) {
    half8v bf[8];
#pragma unroll
    for (int ct = 0; ct < 8; ct++)
      bf[ct] = *reinterpret_cast<const half8v*>(&WT[ct * 16 + l16][kt * 32 + quad * 8]);
#pragma unroll
    for (int rt = 0; rt < 2; rt++)
#pragma unroll
      for (int ct = 0; ct < 8; ct++)
        acc[rt][ct] = __builtin_amdgcn_mfma_f32_16x16x32_f16(af[rt][kt], bf[ct], acc[rt][ct], 0, 0, 0);
  }
#pragma unroll
  for (int rt = 0; rt < 2; rt++) {
#pragma unroll
    for (int r = 0; r < 4; r++) {
      long row = rowbase + rt * 16 + quad * 4 + r;
      float sc = SCALE ? rowscale[row] : 1.f;
#pragma unroll
      for (int ct = 0; ct < 8; ct++) {
        float v = acc[rt][ct][r];
        if (SCALE) v *= sc;
        if (BIAS) v += bias[ct * 16 + l16];
        if (ACT == 1) v = fmaxf(v, 0.f);
        Cout[row * 128 + ct * 16 + l16] = (_Float16)v;
      }
    }
  }
}

// ---------------- fused assignment MLP: 512 blocks x 64 rows ----------------
__global__ __launch_bounds__(256) void mlp_kernel(const _Float16* __restrict__ h2, const _Float16* __restrict__ wta1,
                                                  const _Float16* __restrict__ wta2, const float* __restrict__ ba1,
                                                  const float* __restrict__ ba2, _Float16* __restrict__ sh) {
  __shared__ _Float16 WT1[128][136];
  __shared__ _Float16 Z[64][136];
  const int t = threadIdx.x;
  const int lane = t & 63;
  const int quad = lane >> 4, l16 = lane & 15;
  const int w = t >> 6;
  const long rowbase = (long)(blockIdx.x & 7) * 4096 + (long)(blockIdx.x >> 3) * 64 + w * 16;
  half8v af[4];
#pragma unroll
  for (int kt = 0; kt < 4; kt++)
    af[kt] = *reinterpret_cast<const half8v*>(h2 + (rowbase + l16) * 128 + kt * 32 + quad * 8);
#pragma unroll
  for (int i = 0; i < 8; i++) {
    int idx = i * 256 + t;
    int n = idx >> 4, k8 = (idx & 15) << 3;
    *reinterpret_cast<half8v*>(&WT1[n][k8]) = *reinterpret_cast<const half8v*>(&wta1[n * 128 + k8]);
  }
  __syncthreads();
  {
    floatx4 acc[8];
#pragma unroll
    for (int ct = 0; ct < 8; ct++) acc[ct] = {0.f, 0.f, 0.f, 0.f};
#pragma unroll
    for (int kt = 0; kt < 4; kt++) {
#pragma unroll
      for (int ct = 0; ct < 8; ct++) {
        half8v bf = *reinterpret_cast<const half8v*>(&WT1[ct * 16 + l16][kt * 32 + quad * 8]);
        acc[ct] = __builtin_amdgcn_mfma_f32_16x16x32_f16(af[kt], bf, acc[ct], 0, 0, 0);
      }
    }
#pragma unroll
    for (int r = 0; r < 4; r++) {
      int lrow = w * 16 + quad * 4 + r;
#pragma unroll
      for (int ct = 0; ct < 8; ct++) {
        float v = tanhf(acc[ct][r] + ba1[ct * 16 + l16]);
        Z[lrow][ct * 16 + l16] = (_Float16)v;
      }
    }
  }
  __syncthreads();
#pragma unroll
  for (int i = 0; i < 4; i++) {
    int idx = i * 256 + t;
    int n = idx >> 4, k8 = (idx & 15) << 3;
    *reinterpret_cast<half8v*>(&WT1[n][k8]) = *reinterpret_cast<const half8v*>(&wta2[n * 128 + k8]);
  }
  half8v af2[4];
#pragma unroll
  for (int kt = 0; kt < 4; kt++)
    af2[kt] = *reinterpret_cast<const half8v*>(&Z[w * 16 + l16][kt * 32 + quad * 8]);
  __syncthreads();
  floatx4 acc2[4];
#pragma unroll
  for (int ct = 0; ct < 4; ct++) acc2[ct] = {0.f, 0.f, 0.f, 0.f};
#pragma unroll
  for (int kt = 0; kt < 4; kt++) {
#pragma unroll
    for (int ct = 0; ct < 4; ct++) {
      half8v bf = *reinterpret_cast<const half8v*>(&WT1[ct * 16 + l16][kt * 32 + quad * 8]);
      acc2[ct] = __builtin_amdgcn_mfma_f32_16x16x32_f16(af2[kt], bf, acc2[ct], 0, 0, 0);
    }
  }
#pragma unroll
  for (int r = 0; r < 4; r++) {
    long row = rowbase + quad * 4 + r;
    float v[4];
#pragma unroll
    for (int ct = 0; ct < 4; ct++) v[ct] = acc2[ct][r] + ba2[ct * 16 + l16];
    float m = fmaxf(fmaxf(v[0], v[1]), fmaxf(v[2], v[3]));
#pragma unroll
    for (int off = 1; off <= 8; off <<= 1) m = fmaxf(m, __shfl_xor(m, off, 64));
    float se = 0.f;
#pragma unroll
    for (int ct = 0; ct < 4; ct++) { v[ct] = __expf(v[ct] - m); se += v[ct]; }
#pragma unroll
    for (int off = 1; off <= 8; off <<= 1) se += __shfl_xor(se, off, 64);
    float inv = 1.0f / se;
#pragma unroll
    for (int ct = 0; ct < 4; ct++) v[ct] *= inv;
    float m2 = fmaxf(fmaxf(v[0], v[1]), fmaxf(v[2], v[3]));
#pragma unroll
    for (int off = 1; off <= 8; off <<= 1) m2 = fmaxf(m2, __shfl_xor(m2, off, 64));
    float se2 = 0.f;
#pragma unroll
    for (int ct = 0; ct < 4; ct++) { v[ct] = __expf(v[ct] - m2); se2 += v[ct]; }
#pragma unroll
    for (int off = 1; off <= 8; off <<= 1) se2 += __shfl_xor(se2, off, 64);
    float inv2 = 1.0f / se2;
#pragma unroll
    for (int ct = 0; ct < 4; ct++) sh[row * 64 + ct * 16 + l16] = (_Float16)(v[ct] * inv2);
  }
}

// ---------------- GCN aggregation: 16-stride main + one masked 16-tail ----------------
__global__ __launch_bounds__(256) void aggregate_kernel(const _Float16* __restrict__ hs, const float* __restrict__ dis,
                                                        const int* __restrict__ offs, const int* __restrict__ ssrc,
                                                        const float* __restrict__ bias, _Float16* __restrict__ outh,
                                                        int relu) {
  const int lane = threadIdx.x & 63;
  const int b = blockIdx.x;
  const int node = ((b & 7) << 12) + ((b >> 3) << 2) + (threadIdx.x >> 6);
  const int q = lane >> 4;
  const int fl = (lane & 15) * 8;
  const int e0 = offs[node], e1 = offs[node + 1];
  float fa[8];
#pragma unroll
  for (int j = 0; j < 8; j++) fa[j] = 0.f;
  int e = e0;
  for (; e + 16 <= e1; e += 16) {
    int s0 = ssrc[e + q];
    int s1 = ssrc[e + 4 + q];
    int s2 = ssrc[e + 8 + q];
    int s3 = ssrc[e + 12 + q];
    half8v v0 = *reinterpret_cast<const half8v*>(hs + (size_t)s0 * 128 + fl);
    half8v v1 = *reinterpret_cast<const half8v*>(hs + (size_t)s1 * 128 + fl);
    half8v v2 = *reinterpret_cast<const half8v*>(hs + (size_t)s2 * 128 + fl);
    half8v v3 = *reinterpret_cast<const half8v*>(hs + (size_t)s3 * 128 + fl);
#pragma unroll
    for (int j = 0; j < 8; j++) fa[j] += (float)v0[j] + (float)v1[j] + (float)v2[j] + (float)v3[j];
  }
  if (e < e1) {
    int last = e1 - 1;
    int s[4]; bool m[4];
#pragma unroll
    for (int jj = 0; jj < 4; jj++) {
      int idx = e + jj * 4 + q;
      m[jj] = idx < e1;
      int sv = ssrc[idx < last ? idx : last];
      s[jj] = m[jj] ? sv : node;
    }
#pragma unroll
    for (int jj = 0; jj < 4; jj++) {
      half8v v = *reinterpret_cast<const half8v*>(hs + (size_t)s[jj] * 128 + fl);
      if (m[jj]) {
#pragma unroll
        for (int j = 0; j < 8; j++) fa[j] += (float)v[j];
      }
    }
  }
#pragma unroll
  for (int j = 0; j < 8; j++) {
    fa[j] += __shfl_xor(fa[j], 16, 64);
    fa[j] += __shfl_xor(fa[j], 32, 64);
  }
  if (q == 0) {
    float dn = dis[node];
    half8v self = *reinterpret_cast<const half8v*>(hs + (size_t)node * 128 + fl);
    float4 b0 = *reinterpret_cast<const float4*>(bias + fl);
    float4 b1 = *reinterpret_cast<const float4*>(bias + fl + 4);
    float bb[8] = {b0.x, b0.y, b0.z, b0.w, b1.x, b1.y, b1.z, b1.w};
    half8v r;
#pragma unroll
    for (int j = 0; j < 8; j++) {
      float v = fmaf(fa[j] + (float)self[j], dn, bb[j]);
      if (relu) v = fmaxf(v, 0.f);
      r[j] = (_Float16)v;
    }
    *reinterpret_cast<half8v*>(outh + (size_t)node * 128 + fl) = r;
  }
}

// ---------------- G + den ----------------
__global__ __launch_bounds__(256) void gather_kernel(const _Float16* __restrict__ sh, const int* __restrict__ offs,
                                                     const int* __restrict__ ssrc, _Float16* __restrict__ Gh,
                                                     float* __restrict__ dnp) {
  const int lane = threadIdx.x & 63;
  const int b = blockIdx.x;
  const int node = ((b & 7) << 12) + ((b >> 3) << 2) + (threadIdx.x >> 6);
  const int q = lane >> 3;
  const int fl = (lane & 7) * 8;
  const int e0 = offs[node], e1 = offs[node + 1];
  float fa[8];
  float sq = 0.f;
#pragma unroll
  for (int j = 0; j < 8; j++) fa[j] = 0.f;
  int e = e0;
  for (; e + 16 <= e1; e += 16) {
    int s0 = ssrc[e + q];
    int s1 = ssrc[e + 8 + q];
    half8v v0 = *reinterpret_cast<const half8v*>(sh + (size_t)s0 * 64 + fl);
    half8v v1 = *reinterpret_cast<const half8v*>(sh + (size_t)s1 * 64 + fl);
#pragma unroll
    for (int j = 0; j < 8; j++) {
      float f0 = (float)v0[j], f1 = (float)v1[j];
      fa[j] += f0 + f1;
      sq = fmaf(f0, f0, sq);
      sq = fmaf(f1, f1, sq);
    }
  }
  if (e < e1) {
    int last = e1 - 1;
    int i0 = e + q, i1 = e + 8 + q;
    bool m0 = i0 < e1, m1 = i1 < e1;
    int sv0 = ssrc[i0 < last ? i0 : last];
    int sv1 = ssrc[i1 < last ? i1 : last];
    int s0 = m0 ? sv0 : node;
    int s1 = m1 ? sv1 : node;
    half8v v0 = *reinterpret_cast<const half8v*>(sh + (size_t)s0 * 64 + fl);
    half8v v1 = *reinterpret_cast<const half8v*>(sh + (size_t)s1 * 64 + fl);
#pragma unroll
    for (int j = 0; j < 8; j++) {
      float f0 = m0 ? (float)v0[j] : 0.f;
      float f1 = m1 ? (float)v1[j] : 0.f;
      fa[j] += f0 + f1;
      sq = fmaf(f0, f0, sq);
      sq = fmaf(f1, f1, sq);
    }
  }
#pragma unroll
  for (int j = 0; j < 8; j++) {
    fa[j] += __shfl_xor(fa[j], 8, 64);
    fa[j] += __shfl_xor(fa[j], 16, 64);
    fa[j] += __shfl_xor(fa[j], 32, 64);
  }
  float den = wave_sum(sq);
  if (lane == 0) dnp[node] = den;
  if (q == 0) {
    half8v r;
#pragma unroll
    for (int j = 0; j < 8; j++) r[j] = (_Float16)fa[j];
    *reinterpret_cast<half8v*>(Gh + (size_t)node * 64 + fl) = r;
  }
}

// ---------------- rank reduction via MFMA over 256-node chunks (128 blocks) ----------------
__global__ __launch_bounds__(512) void atb_kernel(const _Float16* __restrict__ sh, const _Float16* __restrict__ Gh,
                                                  const _Float16* __restrict__ h2, float* __restrict__ pF) {
  __shared__ _Float16 XsT[64][136];
  __shared__ _Float16 YsT[256][40];
  const int t = threadIdx.x;
  const int g = blockIdx.x & 7, chunk = blockIdx.x >> 3;
  const int n0 = g * 4096 + chunk * 256;
  const int lane = t & 63;
  const int w = t >> 6;
  const int mtile = w & 3;
  const int nhalf = w >> 2;
  const int quad = lane >> 4, l16 = lane & 15;

  floatx4 acc[8];
#pragma unroll
  for (int nt = 0; nt < 8; nt++) acc[nt] = {0.f, 0.f, 0.f, 0.f};

  for (int half = 0; half < 2; ++half) {
    const int hb = n0 + half * 128;
    __syncthreads();
#pragma unroll
    for (int i = 0; i < 4; i++) {
      int slot = i * 512 + t;
      int k = slot >> 4, c4 = (slot & 15) * 4;
      half4v v = *reinterpret_cast<const half4v*>(&sh[(size_t)(hb + k) * 64 + c4]);
#pragma unroll
      for (int j = 0; j < 4; j++) XsT[c4 + j][k] = v[j];
    }
    for (int kt = 0; kt < 4; ++kt) {
      const int nb = hb + kt * 32;
      __syncthreads();
#pragma unroll
      for (int i = 0; i < 4; i++) {
        int slot = i * 512 + t;
        int cg = slot & 15, k = (slot >> 4) & 31, ch = slot >> 9;
        int c = ch * 64 + cg * 4;
        half4v v;
        if (c < 64)       v = *reinterpret_cast<const half4v*>(&Gh[(size_t)(nb + k) * 64 + c]);
        else if (c < 128) v = *reinterpret_cast<const half4v*>(&sh[(size_t)(nb + k) * 64 + (c - 64)]);
        else              v = *reinterpret_cast<const half4v*>(&h2[(size_t)(nb + k) * 128 + (c - 128)]);
#pragma unroll
        for (int j = 0; j < 4; j++) YsT[c + j][k] = v[j];
      }
      __syncthreads();
      half8v af = *reinterpret_cast<const half8v*>(&XsT[mtile * 16 + l16][kt * 32 + quad * 8]);
#pragma unroll
      for (int nt = 0; nt < 8; nt++) {
        half8v bf = *reinterpret_cast<const half8v*>(&YsT[(nhalf * 8 + nt) * 16 + l16][quad * 8]);
        acc[nt] = __builtin_amdgcn_mfma_f32_16x16x32_f16(af, bf, acc[nt], 0, 0, 0);
      }
    }
  }
  float* dst = pF + (size_t)blockIdx.x * 16384;
#pragma unroll
  for (int nt = 0; nt < 8; nt++) {
#pragma unroll
    for (int r = 0; r < 4; r++) {
      dst[(mtile * 16 + quad * 4 + r) * 256 + (nhalf * 8 + nt) * 16 + l16] = acc[nt][r];
    }
  }
}

// ---------------- merge 16 partials/graph ----------------
__global__ __launch_bounds__(256) void merge_kernel(const float* __restrict__ pF, float* __restrict__ oadj,
                                                    float* __restrict__ ssb, _Float16* __restrict__ outp16) {
  int g = blockIdx.x & 7;
  int o4 = (blockIdx.x >> 3) * 256 + threadIdx.x;
  float sx = 0.f, sy = 0.f, sz = 0.f, sw = 0.f;
#pragma unroll
  for (int q = 0; q < 16; ++q) {
    float4 v = *reinterpret_cast<const float4*>(pF + (size_t)(q * 8 + g) * 16384 + o4 * 4);
    sx += v.x; sy += v.y; sz += v.z; sw += v.w;
  }
  int row = o4 >> 6;
  int c = (o4 & 63) * 4;
  if (c < 64) {
    float4 o = {sx, sy, sz, sw};
    *reinterpret_cast<float4*>(&oadj[g * 4096 + row * 64 + c]) = o;
  } else if (c < 128) {
    float4 o = {sx, sy, sz, sw};
    *reinterpret_cast<float4*>(&ssb[g * 4096 + row * 64 + (c - 64)]) = o;
  } else {
    half4v h = {(_Float16)sx, (_Float16)sy, (_Float16)sz, (_Float16)sw};
    *reinterpret_cast<half4v*>(&outp16[g * 8192 + row * 128 + (c - 128)]) = h;
  }
}

// ---------------- epilogue2 ----------------
__global__ __launch_bounds__(256) void epilogue2_kernel(const float* __restrict__ oadj, const float* __restrict__ ssb,
                                                        const _Float16* __restrict__ outp16, const _Float16* __restrict__ wto,
                                                        const float* __restrict__ bo, const float* __restrict__ dn,
                                                        float* __restrict__ out) {
  __shared__ _Float16 outpS[64][136];
  __shared__ _Float16 WoT[128][136];
  __shared__ float red[256];
  __shared__ float rowsum[64];
  __shared__ float dw[4], w1[4], w2[4], w3[4];
  const int g = blockIdx.x, t = threadIdx.x;

#pragma unroll
  for (int i = 0; i < 8; i++) {
    int idx = i * 256 + t;
    int n = idx >> 4, k8 = (idx & 15) << 3;
    *reinterpret_cast<half8v*>(&WoT[n][k8]) = *reinterpret_cast<const half8v*>(&wto[n * 128 + k8]);
  }
#pragma unroll
  for (int i = 0; i < 4; i++) {
    int idx = i * 256 + t;
    int orow = idx >> 4, c8 = (idx & 15) * 8;
    half8v v = *reinterpret_cast<const half8v*>(&outp16[g * 8192 + orow * 128 + c8]);
    *reinterpret_cast<half8v*>(&outpS[orow][c8]) = v;
  }

  const int row = t >> 2, p = t & 3;
  float Areg[16];
  float trs_p = 0.f, ssq_p = 0.f;
#pragma unroll
  for (int c4 = 0; c4 < 4; c4++) {
    float4 a = *reinterpret_cast<const float4*>(&oadj[g * 4096 + row * 64 + p * 16 + c4 * 4]);
    Areg[c4 * 4 + 0] = a.x; Areg[c4 * 4 + 1] = a.y; Areg[c4 * 4 + 2] = a.z; Areg[c4 * 4 + 3] = a.w;
    float4 s = *reinterpret_cast<const float4*>(&ssb[g * 4096 + row * 64 + p * 16 + c4 * 4]);
    float vv[4] = {s.x, s.y, s.z, s.w};
#pragma unroll
    for (int jj = 0; jj < 4; jj++) {
      ssq_p += vv[jj] * vv[jj];
      int col = p * 16 + c4 * 4 + jj;
      if (col == row) trs_p += vv[jj];
    }
  }
  float da = 0.f;
#pragma unroll
  for (int i = 0; i < 16; i++) da += dn[g * 4096 + i * 256 + t];
  float dws = wave_sum(da);
  if ((t & 63) == 0) dw[t >> 6] = dws;

  float rs = 0.f, tra = 0.f;
#pragma unroll
  for (int c = 0; c < 16; c++) {
    int j = p * 16 + c;
    if (j == row) tra += Areg[c];
    else rs += Areg[c];
  }
  red[t] = rs;
  __syncthreads();
  if (p == 0) rowsum[row] = red[t] + red[t + 1] + red[t + 2] + red[t + 3];
  float v1 = wave_sum(tra), v2 = wave_sum(trs_p), v3 = wave_sum(ssq_p);
  if ((t & 63) == 0) { int w = t >> 6; w1[w] = v1; w2[w] = v2; w3[w] = v3; }
  __syncthreads();
  if (t == 0) {
    float TRA = w1[0] + w1[1] + w1[2] + w1[3];
    float TRS = w2[0] + w2[1] + w2[2] + w2[3];
    float SSQ = w3[0] + w3[1] + w3[2] + w3[3];
    float DEN = dw[0] + dw[1] + dw[2] + dw[3];
    atomicAdd(&out[98816], -(TRA / DEN) * 0.125f);
    float ssn = sqrtf(SSQ);
    atomicAdd(&out[98817], sqrtf(2.0f - TRS / (4.0f * ssn)) * 0.125f);
  }
  float di = sqrtf(rowsum[row]) + 1e-15f;
#pragma unroll
  for (int c = 0; c < 16; c++) {
    int j = p * 16 + c;
    float v = (j == row) ? 0.f : Areg[c];
    float dj = sqrtf(rowsum[j]) + 1e-15f;
    out[65536 + g * 4096 + row * 64 + j] = v / (di * dj);
  }
  if (t < 64) out[98304 + g * 64 + t] = (float)g;

  const int lane = t & 63;
  const int quad = lane >> 4, l16 = lane & 15;
  const int w = t >> 6;
  floatx4 acc[8];
#pragma unroll
  for (int ct = 0; ct < 8; ct++) acc[ct] = {0.f, 0.f, 0.f, 0.f};
#pragma unroll
  for (int kt = 0; kt < 4; kt++) {
    half8v af = *reinterpret_cast<const half8v*>(&outpS[w * 16 + l16][kt * 32 + quad * 8]);
#pragma unroll
    for (int ct = 0; ct < 8; ct++) {
      half8v bf = *reinterpret_cast<const half8v*>(&WoT[ct * 16 + l16][kt * 32 + quad * 8]);
      acc[ct] = __builtin_amdgcn_mfma_f32_16x16x32_f16(af, bf, acc[ct], 0, 0, 0);
    }
  }
#pragma unroll
  for (int r = 0; r < 4; r++) {
    int orow = w * 16 + quad * 4 + r;
#pragma unroll
    for (int ct = 0; ct < 8; ct++) {
      int col = ct * 16 + l16;
      float v = fmaxf(acc[ct][r] + bo[col], 0.f);
      out[(g * 64 + orow) * 128 + col] = v;
    }
  }
}

extern "C" void kernel_launch(void* const* d_in, const int* in_sizes, int n_in,
                              void* d_out, int out_size, void* d_ws, size_t ws_size,
                              hipStream_t stream) {
  const float* x   = (const float*)d_in[0];
  const int*   ei  = (const int*)d_in[1];
  const float* W1  = (const float*)d_in[3];
  const float* b1  = (const float*)d_in[4];
  const float* W2  = (const float*)d_in[5];
  const float* b2  = (const float*)d_in[6];
  const float* Wa1 = (const float*)d_in[7];
  const float* ba1 = (const float*)d_in[8];
  const float* Wa2 = (const float*)d_in[9];
  const float* ba2 = (const float*)d_in[10];
  const float* Wo  = (const float*)d_in[11];
  const float* bo  = (const float*)d_in[12];
  const int* src = ei;
  const int* dst = ei + NEDGES;
  float* out = (float*)d_out;

  char* ws = (char*)d_ws;
  size_t o = 0;
  auto alloc = [&](size_t bytes) -> void* {
    void* p = ws + o;
    o += (bytes + 255) & ~(size_t)255;
    return p;
  };
  _Float16* h16A = (_Float16*)alloc((size_t)NNODES * 128 * 2);
  _Float16* h16B = (_Float16*)alloc((size_t)NNODES * 128 * 2);
  _Float16* h16C = (_Float16*)alloc((size_t)NNODES * 128 * 2);
  _Float16* sh   = (_Float16*)alloc((size_t)NNODES * 64 * 2);
  _Float16* Gh   = (_Float16*)alloc((size_t)NNODES * 64 * 2);
  float* pF    = (float*)alloc((size_t)128 * 16384 * 4);   // 8 MB
  float* dis   = (float*)alloc((size_t)NNODES * 4);
  int* offs    = (int*)alloc((size_t)(NNODES + 1) * 4);
  int* ssrc    = (int*)alloc((size_t)NEDGES * 4);
  unsigned short* rank16 = (unsigned short*)alloc((size_t)NEDGES * 2);
  int* pIn     = (int*)alloc((size_t)8 * CPG * 4096 * 4);
  int* cbase   = (int*)alloc((size_t)8 * CPG * 4096 * 4);
  float* dn    = (float*)alloc((size_t)NNODES * 4);
  float* oadj  = (float*)alloc(8 * 4096 * 4);
  float* ssb   = (float*)alloc(8 * 4096 * 4);
  _Float16* outp16 = (_Float16*)alloc(8 * 8192 * 2);
  _Float16* wt16   = (_Float16*)alloc((size_t)WT_TOTAL * 2);

  hipMemsetAsync(out + 98816, 0, 2 * sizeof(float), stream);

  histmm_kernel<<<384, 256, 0, stream>>>(src, dst, pIn, rank16, W1, W2, Wa1, Wa2, Wo, wt16, x, h16A);
  scan2_kernel<<<8, 1024, 0, stream>>>(pIn, offs, cbase, dis);
  scatter3_kernel<<<128, 256, 0, stream>>>(src, dst, rank16, cbase, ssrc, dis, h16A);

  aggregate_kernel<<<NNODES / 4, 256, 0, stream>>>(h16A, dis, offs, ssrc, b1, h16B, 1);
  mgemm_kernel<0, 0, 1, 0><<<NNODES / 128, 256, 0, stream>>>(h16B, wt16 + WT2_OFF, nullptr, dis, h16A);
  aggregate_kernel<<<NNODES / 4, 256, 0, stream>>>(h16A, dis, offs, ssrc, b2, h16C, 0);

  mlp_kernel<<<NNODES / 64, 256, 0, stream>>>(h16C, wt16 + WTA1_OFF, wt16 + WTA2_OFF, ba1, ba2, sh);

  gather_kernel<<<NNODES / 4, 256, 0, stream>>>(sh, offs, ssrc, Gh, dn);
  atb_kernel<<<128, 512, 0, stream>>>(sh, Gh, h16C, pF);
  merge_kernel<<<128, 256, 0, stream>>>(pF, oadj, ssb, outp16);
  epilogue2_kernel<<<8, 256, 0, stream>>>(oadj, ssb, outp16, wt16 + WTO_OFF, bo, dn, out);
}

// Round 16
// 195.224 us; speedup vs baseline: 1.0435x; 1.0435x over previous
//
#include <hip/hip_runtime.h>

#define NNODES 32768
#define NEDGES 524288
#define KCL 64
#define CPG 16   // histogram chunks per graph (4096 edges each)

typedef _Float16 half8v __attribute__((ext_vector_type(8)));
typedef _Float16 half4v __attribute__((ext_vector_type(4)));
typedef float floatx4 __attribute__((ext_vector_type(4)));

// fp16 transposed weight buffer layout (element offsets into wt16):
#define WT1_OFF   0       // W1  [128x128] -> [n*128+k]
#define WT2_OFF   16384   // W2  [128x128]
#define WTA1_OFF  32768   // Wa1 [128x128]
#define WTA2_OFF  49152   // Wa2 [128x64]  -> [n*128+k], n<64
#define WTO_OFF   57344   // Wo  [128x128]
#define WT_TOTAL  73728

__device__ __forceinline__ float wave_sum(float v) {
#pragma unroll
  for (int off = 32; off > 0; off >>= 1) v += __shfl_xor(v, off, 64);
  return v;
}

// ---------------- per-chunk LDS histogram (XCD-swizzled, int4 edge loads) + weight prep ----------------
__global__ __launch_bounds__(256) void hist2_kernel(const int* __restrict__ src, const int* __restrict__ dst,
                                                    int* __restrict__ pIn,
                                                    const float* __restrict__ W1, const float* __restrict__ W2,
                                                    const float* __restrict__ Wa1, const float* __restrict__ Wa2,
                                                    const float* __restrict__ Wo, _Float16* __restrict__ wt16) {
  __shared__ int hIn[4096];
  const int t = threadIdx.x;
  const int g = blockIdx.x & 7;
  const int chunk = blockIdx.x >> 3;
  const int ebase = (g << 16) + (chunk << 12);
  const int nbase = g << 12;
  for (int i = t; i < 4096; i += 256) hIn[i] = 0;
  __syncthreads();
  {
    int tg = blockIdx.x * 256 + t;
#pragma unroll
    for (int i = 0; i < 3; i++) {
      int id = tg + i * 32768;
      if (id < WT_TOTAL) {
        const float* W; int base, BN;
        if (id < 16384)      { W = W1;  base = WT1_OFF;  BN = 128; }
        else if (id < 32768) { W = W2;  base = WT2_OFF;  BN = 128; }
        else if (id < 49152) { W = Wa1; base = WTA1_OFF; BN = 128; }
        else if (id < 57344) { W = Wa2; base = WTA2_OFF; BN = 64; }
        else                 { W = Wo;  base = WTO_OFF;  BN = 128; }
        int m = id - base;
        int k = m / BN, n = m % BN;
        wt16[base + n * 128 + k] = (_Float16)W[m];
      }
    }
  }
  const int4* dst4 = reinterpret_cast<const int4*>(dst + ebase);
#pragma unroll
  for (int i = 0; i < 4; ++i) {
    int4 d = dst4[i * 256 + t];
    atomicAdd(&hIn[d.x - nbase], 1);
    atomicAdd(&hIn[d.y - nbase], 1);
    atomicAdd(&hIn[d.z - nbase], 1);
    atomicAdd(&hIn[d.w - nbase], 1);
  }
  __syncthreads();
  int* dIn = pIn + ((size_t)(g * CPG + chunk) << 12);
  for (int i = t; i < 4096; i += 256) dIn[i] = hIn[i];
}

// ---------------- per-graph scan: offs, dis, per-chunk cursor bases ----------------
__global__ __launch_bounds__(1024) void scan2_kernel(const int* __restrict__ pIn, int* __restrict__ offs,
                                                     int* __restrict__ cbase, float* __restrict__ dis) {
  __shared__ int part[1024];
  const int t = threadIdx.x;
  const int g = blockIdx.x;
  int tot[4];
  int s = 0;
#pragma unroll
  for (int j = 0; j < 4; ++j) {
    int l = t * 4 + j;
    int cnt = 0;
#pragma unroll
    for (int c = 0; c < CPG; ++c) cnt += pIn[(((size_t)(g * CPG + c)) << 12) + l];
    tot[j] = cnt;
    s += cnt;
  }
  part[t] = s;
  __syncthreads();
  for (int off = 1; off < 1024; off <<= 1) {
    int add = (t >= off) ? part[t - off] : 0;
    __syncthreads();
    part[t] += add;
    __syncthreads();
  }
  int run = (g << 16) + ((t == 0) ? 0 : part[t - 1]);
#pragma unroll
  for (int j = 0; j < 4; ++j) {
    int l = t * 4 + j;
    int n = (g << 12) + l;
    offs[n] = run;
    dis[n] = rsqrtf((float)tot[j] + 1.0f);
    int running = run;
#pragma unroll
    for (int c = 0; c < CPG; ++c) {
      size_t idx = (((size_t)(g * CPG + c)) << 12) + l;
      cbase[idx] = running;
      running += pIn[idx];
    }
    run += tot[j];
  }
  if (g == 0 && t == 0) offs[NNODES] = NEDGES;
}

// ---------------- scatter via LDS cursors (XCD-swizzled, int4 edge loads) ----------------
__global__ __launch_bounds__(256) void scatter2_kernel(const int* __restrict__ src, const int* __restrict__ dst,
                                                       const int* __restrict__ cbase, int* __restrict__ ssrc) {
  __shared__ int cur[4096];
  const int t = threadIdx.x;
  const int g = blockIdx.x & 7;
  const int chunk = blockIdx.x >> 3;
  const int ebase = (g << 16) + (chunk << 12);
  const int nbase = g << 12;
  const int* cb = cbase + ((size_t)(g * CPG + chunk) << 12);
  for (int i = t; i < 4096; i += 256) cur[i] = cb[i];
  __syncthreads();
  const int4* dst4 = reinterpret_cast<const int4*>(dst + ebase);
  const int4* src4 = reinterpret_cast<const int4*>(src + ebase);
#pragma unroll
  for (int i = 0; i < 4; ++i) {
    int4 d = dst4[i * 256 + t];
    int4 s = src4[i * 256 + t];
    int p0 = atomicAdd(&cur[d.x - nbase], 1); ssrc[p0] = s.x;
    int p1 = atomicAdd(&cur[d.y - nbase], 1); ssrc[p1] = s.y;
    int p2 = atomicAdd(&cur[d.z - nbase], 1); ssrc[p2] = s.z;
    int p3 = atomicAdd(&cur[d.w - nbase], 1); ssrc[p3] = s.w;
  }
}

// ---------------- MFMA fp16 GEMM: C[M x 128] = A[M x 128] @ W, W pre-transposed fp16 ----------------
template <int ACT, int BIAS, int SCALE, int AFP32>
__global__ __launch_bounds__(256) void mgemm_kernel(const void* __restrict__ Ain, const _Float16* __restrict__ WT16,
                                                    const float* __restrict__ bias, const float* __restrict__ rowscale,
                                                    _Float16* __restrict__ Cout) {
  __shared__ _Float16 WT[128][136];
  const int t = threadIdx.x;
  const int lane = t & 63;
  const int quad = lane >> 4, l16 = lane & 15;
  const long rowbase = (long)(blockIdx.x & 7) * 4096 + (long)(blockIdx.x >> 3) * 128 + (t >> 6) * 32;
  half8v af[2][4];
#pragma unroll
  for (int rt = 0; rt < 2; rt++)
#pragma unroll
    for (int kt = 0; kt < 4; kt++) {
      if (AFP32) {
        const float* A32 = (const float*)Ain;
        const float* p = A32 + (rowbase + rt * 16 + l16) * 128 + kt * 32 + quad * 8;
        float4 p0 = *reinterpret_cast<const float4*>(p);
        float4 p1 = *reinterpret_cast<const float4*>(p + 4);
        half8v h = {(_Float16)p0.x, (_Float16)p0.y, (_Float16)p0.z, (_Float16)p0.w,
                    (_Float16)p1.x, (_Float16)p1.y, (_Float16)p1.z, (_Float16)p1.w};
        af[rt][kt] = h;
      } else {
        const _Float16* A16 = (const _Float16*)Ain;
        af[rt][kt] = *reinterpret_cast<const half8v*>(A16 + (rowbase + rt * 16 + l16) * 128 + kt * 32 + quad * 8);
      }
    }
#pragma unroll
  for (int i = 0; i < 8; i++) {
    int idx = i * 256 + t;
    int n = idx >> 4, k8 = (idx & 15) << 3;
    *reinterpret_cast<half8v*>(&WT[n][k8]) = *reinterpret_cast<const half8v*>(&WT16[n * 128 + k8]);
  }
  __syncthreads();
  floatx4 acc[2][8];
#pragma unroll
  for (int rt = 0; rt < 2; rt++)
#pragma unroll
    for (int ct = 0; ct < 8; ct++) acc[rt][ct] = {0.f, 0.f, 0.f, 0.f};
#pragma unroll
  for (int kt = 0; kt < 4; kt++) {
    half8v bf[8];
#pragma unroll
    for (int ct = 0; ct < 8; ct++)
      bf[ct] = *reinterpret_cast<const half8v*>(&WT[ct * 16 + l16][kt * 32 + quad * 8]);
#pragma unroll
    for (int rt = 0; rt < 2; rt++)
#pragma unroll
      for (int ct = 0; ct < 8; ct++)
        acc[rt][ct] = __builtin_amdgcn_mfma_f32_16x16x32_f16(af[rt][kt], bf[ct], acc[rt][ct], 0, 0, 0);
  }
#pragma unroll
  for (int rt = 0; rt < 2; rt++) {
#pragma unroll
    for (int r = 0; r < 4; r++) {
      long row = rowbase + rt * 16 + quad * 4 + r;
      float sc = SCALE ? rowscale[row] : 1.f;
#pragma unroll
      for (int ct = 0; ct < 8; ct++) {
        float v = acc[rt][ct][r];
        if (SCALE) v *= sc;
        if (BIAS) v += bias[ct * 16 + l16];
        if (ACT == 1) v = fmaxf(v, 0.f);
        Cout[row * 128 + ct * 16 + l16] = (_Float16)v;
      }
    }
  }
}

// ---------------- fused assignment MLP: 512 blocks x 64 rows ----------------
__global__ __launch_bounds__(256) void mlp_kernel(const _Float16* __restrict__ h2, const _Float16* __restrict__ wta1,
                                                  const _Float16* __restrict__ wta2, const float* __restrict__ ba1,
                                                  const float* __restrict__ ba2, _Float16* __restrict__ sh) {
  __shared__ _Float16 WT1[128][136];
  __shared__ _Float16 Z[64][136];
  const int t = threadIdx.x;
  const int lane = t & 63;
  const int quad = lane >> 4, l16 = lane & 15;
  const int w = t >> 6;
  const long rowbase = (long)(blockIdx.x & 7) * 4096 + (long)(blockIdx.x >> 3) * 64 + w * 16;
  half8v af[4];
#pragma unroll
  for (int kt = 0; kt < 4; kt++)
    af[kt] = *reinterpret_cast<const half8v*>(h2 + (rowbase + l16) * 128 + kt * 32 + quad * 8);
#pragma unroll
  for (int i = 0; i < 8; i++) {
    int idx = i * 256 + t;
    int n = idx >> 4, k8 = (idx & 15) << 3;
    *reinterpret_cast<half8v*>(&WT1[n][k8]) = *reinterpret_cast<const half8v*>(&wta1[n * 128 + k8]);
  }
  __syncthreads();
  {
    floatx4 acc[8];
#pragma unroll
    for (int ct = 0; ct < 8; ct++) acc[ct] = {0.f, 0.f, 0.f, 0.f};
#pragma unroll
    for (int kt = 0; kt < 4; kt++) {
#pragma unroll
      for (int ct = 0; ct < 8; ct++) {
        half8v bf = *reinterpret_cast<const half8v*>(&WT1[ct * 16 + l16][kt * 32 + quad * 8]);
        acc[ct] = __builtin_amdgcn_mfma_f32_16x16x32_f16(af[kt], bf, acc[ct], 0, 0, 0);
      }
    }
#pragma unroll
    for (int r = 0; r < 4; r++) {
      int lrow = w * 16 + quad * 4 + r;
#pragma unroll
      for (int ct = 0; ct < 8; ct++) {
        float v = tanhf(acc[ct][r] + ba1[ct * 16 + l16]);
        Z[lrow][ct * 16 + l16] = (_Float16)v;
      }
    }
  }
  __syncthreads();
#pragma unroll
  for (int i = 0; i < 4; i++) {
    int idx = i * 256 + t;
    int n = idx >> 4, k8 = (idx & 15) << 3;
    *reinterpret_cast<half8v*>(&WT1[n][k8]) = *reinterpret_cast<const half8v*>(&wta2[n * 128 + k8]);
  }
  half8v af2[4];
#pragma unroll
  for (int kt = 0; kt < 4; kt++)
    af2[kt] = *reinterpret_cast<const half8v*>(&Z[w * 16 + l16][kt * 32 + quad * 8]);
  __syncthreads();
  floatx4 acc2[4];
#pragma unroll
  for (int ct = 0; ct < 4; ct++) acc2[ct] = {0.f, 0.f, 0.f, 0.f};
#pragma unroll
  for (int kt = 0; kt < 4; kt++) {
#pragma unroll
    for (int ct = 0; ct < 4; ct++) {
      half8v bf = *reinterpret_cast<const half8v*>(&WT1[ct * 16 + l16][kt * 32 + quad * 8]);
      acc2[ct] = __builtin_amdgcn_mfma_f32_16x16x32_f16(af2[kt], bf, acc2[ct], 0, 0, 0);
    }
  }
#pragma unroll
  for (int r = 0; r < 4; r++) {
    long row = rowbase + quad * 4 + r;
    float v[4];
#pragma unroll
    for (int ct = 0; ct < 4; ct++) v[ct] = acc2[ct][r] + ba2[ct * 16 + l16];
    float m = fmaxf(fmaxf(v[0], v[1]), fmaxf(v[2], v[3]));
#pragma unroll
    for (int off = 1; off <= 8; off <<= 1) m = fmaxf(m, __shfl_xor(m, off, 64));
    float se = 0.f;
#pragma unroll
    for (int ct = 0; ct < 4; ct++) { v[ct] = __expf(v[ct] - m); se += v[ct]; }
#pragma unroll
    for (int off = 1; off <= 8; off <<= 1) se += __shfl_xor(se, off, 64);
    float inv = 1.0f / se;
#pragma unroll
    for (int ct = 0; ct < 4; ct++) v[ct] *= inv;
    float m2 = fmaxf(fmaxf(v[0], v[1]), fmaxf(v[2], v[3]));
#pragma unroll
    for (int off = 1; off <= 8; off <<= 1) m2 = fmaxf(m2, __shfl_xor(m2, off, 64));
    float se2 = 0.f;
#pragma unroll
    for (int ct = 0; ct < 4; ct++) { v[ct] = __expf(v[ct] - m2); se2 += v[ct]; }
#pragma unroll
    for (int off = 1; off <= 8; off <<= 1) se2 += __shfl_xor(se2, off, 64);
    float inv2 = 1.0f / se2;
#pragma unroll
    for (int ct = 0; ct < 4; ct++) sh[row * 64 + ct * 16 + l16] = (_Float16)(v[ct] * inv2);
  }
}

// ---------------- GCN aggregation: 16-stride main + one masked 16-tail ----------------
__global__ __launch_bounds__(256) void aggregate_kernel(const _Float16* __restrict__ hs, const float* __restrict__ dis,
                                                        const int* __restrict__ offs, const int* __restrict__ ssrc,
                                                        const float* __restrict__ bias, _Float16* __restrict__ outh,
                                                        int relu) {
  const int lane = threadIdx.x & 63;
  const int b = blockIdx.x;
  const int node = ((b & 7) << 12) + ((b >> 3) << 2) + (threadIdx.x >> 6);
  const int q = lane >> 4;
  const int fl = (lane & 15) * 8;
  const int e0 = offs[node], e1 = offs[node + 1];
  float fa[8];
#pragma unroll
  for (int j = 0; j < 8; j++) fa[j] = 0.f;
  int e = e0;
  for (; e + 16 <= e1; e += 16) {
    int s0 = ssrc[e + q];
    int s1 = ssrc[e + 4 + q];
    int s2 = ssrc[e + 8 + q];
    int s3 = ssrc[e + 12 + q];
    half8v v0 = *reinterpret_cast<const half8v*>(hs + (size_t)s0 * 128 + fl);
    half8v v1 = *reinterpret_cast<const half8v*>(hs + (size_t)s1 * 128 + fl);
    half8v v2 = *reinterpret_cast<const half8v*>(hs + (size_t)s2 * 128 + fl);
    half8v v3 = *reinterpret_cast<const half8v*>(hs + (size_t)s3 * 128 + fl);
#pragma unroll
    for (int j = 0; j < 8; j++) fa[j] += (float)v0[j] + (float)v1[j] + (float)v2[j] + (float)v3[j];
  }
  if (e < e1) {
    int last = e1 - 1;
    int s[4]; bool m[4];
#pragma unroll
    for (int jj = 0; jj < 4; jj++) {
      int idx = e + jj * 4 + q;
      m[jj] = idx < e1;
      int sv = ssrc[idx < last ? idx : last];
      s[jj] = m[jj] ? sv : node;
    }
#pragma unroll
    for (int jj = 0; jj < 4; jj++) {
      half8v v = *reinterpret_cast<const half8v*>(hs + (size_t)s[jj] * 128 + fl);
      if (m[jj]) {
#pragma unroll
        for (int j = 0; j < 8; j++) fa[j] += (float)v[j];
      }
    }
  }
#pragma unroll
  for (int j = 0; j < 8; j++) {
    fa[j] += __shfl_xor(fa[j], 16, 64);
    fa[j] += __shfl_xor(fa[j], 32, 64);
  }
  if (q == 0) {
    float dn = dis[node];
    half8v self = *reinterpret_cast<const half8v*>(hs + (size_t)node * 128 + fl);
    float4 b0 = *reinterpret_cast<const float4*>(bias + fl);
    float4 b1 = *reinterpret_cast<const float4*>(bias + fl + 4);
    float bb[8] = {b0.x, b0.y, b0.z, b0.w, b1.x, b1.y, b1.z, b1.w};
    half8v r;
#pragma unroll
    for (int j = 0; j < 8; j++) {
      float v = fmaf(fa[j] + (float)self[j], dn, bb[j]);
      if (relu) v = fmaxf(v, 0.f);
      r[j] = (_Float16)v;
    }
    *reinterpret_cast<half8v*>(outh + (size_t)node * 128 + fl) = r;
  }
}

// ---------------- G + den: 16-stride main + one masked 16-tail ----------------
__global__ __launch_bounds__(256) void gather_kernel(const _Float16* __restrict__ sh, const int* __restrict__ offs,
                                                     const int* __restrict__ ssrc, _Float16* __restrict__ Gh,
                                                     float* __restrict__ dnp) {
  const int lane = threadIdx.x & 63;
  const int b = blockIdx.x;
  const int node = ((b & 7) << 12) + ((b >> 3) << 2) + (threadIdx.x >> 6);
  const int q = lane >> 3;
  const int fl = (lane & 7) * 8;
  const int e0 = offs[node], e1 = offs[node + 1];
  float fa[8];
  float sq = 0.f;
#pragma unroll
  for (int j = 0; j < 8; j++) fa[j] = 0.f;
  int e = e0;
  for (; e + 16 <= e1; e += 16) {
    int s0 = ssrc[e + q];
    int s1 = ssrc[e + 8 + q];
    half8v v0 = *reinterpret_cast<const half8v*>(sh + (size_t)s0 * 64 + fl);
    half8v v1 = *reinterpret_cast<const half8v*>(sh + (size_t)s1 * 64 + fl);
#pragma unroll
    for (int j = 0; j < 8; j++) {
      float f0 = (float)v0[j], f1 = (float)v1[j];
      fa[j] += f0 + f1;
      sq = fmaf(f0, f0, sq);
      sq = fmaf(f1, f1, sq);
    }
  }
  if (e < e1) {
    int last = e1 - 1;
    int i0 = e + q, i1 = e + 8 + q;
    bool m0 = i0 < e1, m1 = i1 < e1;
    int sv0 = ssrc[i0 < last ? i0 : last];
    int sv1 = ssrc[i1 < last ? i1 : last];
    int s0 = m0 ? sv0 : node;
    int s1 = m1 ? sv1 : node;
    half8v v0 = *reinterpret_cast<const half8v*>(sh + (size_t)s0 * 64 + fl);
    half8v v1 = *reinterpret_cast<const half8v*>(sh + (size_t)s1 * 64 + fl);
#pragma unroll
    for (int j = 0; j < 8; j++) {
      float f0 = m0 ? (float)v0[j] : 0.f;
      float f1 = m1 ? (float)v1[j] : 0.f;
      fa[j] += f0 + f1;
      sq = fmaf(f0, f0, sq);
      sq = fmaf(f1, f1, sq);
    }
  }
#pragma unroll
  for (int j = 0; j < 8; j++) {
    fa[j] += __shfl_xor(fa[j], 8, 64);
    fa[j] += __shfl_xor(fa[j], 16, 64);
    fa[j] += __shfl_xor(fa[j], 32, 64);
  }
  float den = wave_sum(sq);
  if (lane == 0) dnp[node] = den;
  if (q == 0) {
    half8v r;
#pragma unroll
    for (int j = 0; j < 8; j++) r[j] = (_Float16)fa[j];
    *reinterpret_cast<half8v*>(Gh + (size_t)node * 64 + fl) = r;
  }
}

// ---------------- rank reduction via MFMA: C[64 x 256] = s_chunk^T [G | s | h2] ----------------
// 256 blocks (8 graphs x 32 chunks of 128 nodes), 512 threads (8 waves: 4 m-tiles x 2 n-halves).
__global__ __launch_bounds__(512) void atb_kernel(const _Float16* __restrict__ sh, const _Float16* __restrict__ Gh,
                                                  const _Float16* __restrict__ h2, float* __restrict__ pF) {
  __shared__ _Float16 XsT[64][136];   // [cluster m][node k 0..127]
  __shared__ _Float16 YsT[256][40];   // [col n][node k 0..31 within kt]
  const int t = threadIdx.x;
  const int g = blockIdx.x & 7, chunk = blockIdx.x >> 3;
  const int n0 = g * 4096 + chunk * 128;
  const int lane = t & 63;
  const int w = t >> 6;
  const int mtile = w & 3;
  const int nhalf = w >> 2;
  const int quad = lane >> 4, l16 = lane & 15;

  // stage XsT = s^T : slots (k 0..127, c4 0..15); coalesced 128B row reads
#pragma unroll
  for (int i = 0; i < 4; i++) {
    int slot = i * 512 + t;
    int k = slot >> 4, c4 = (slot & 15) * 4;
    half4v v = *reinterpret_cast<const half4v*>(&sh[(size_t)(n0 + k) * 64 + c4]);
#pragma unroll
    for (int j = 0; j < 4; j++) XsT[c4 + j][k] = v[j];
  }

  floatx4 acc[8];
#pragma unroll
  for (int nt = 0; nt < 8; nt++) acc[nt] = {0.f, 0.f, 0.f, 0.f};

  for (int kt = 0; kt < 4; ++kt) {
    const int nb = n0 + kt * 32;
    __syncthreads();  // protect YsT reuse (kt>0); XsT staged at kt=0
    // stage YsT: cg=slot&15, k=(slot>>4)&31, ch=slot>>9; c = ch*64+cg*4
#pragma unroll
    for (int i = 0; i < 4; i++) {
      int slot = i * 512 + t;
      int cg = slot & 15, k = (slot >> 4) & 31, ch = slot >> 9;
      int c = ch * 64 + cg * 4;
      half4v v;
      if (c < 64)       v = *reinterpret_cast<const half4v*>(&Gh[(size_t)(nb + k) * 64 + c]);
      else if (c < 128) v = *reinterpret_cast<const half4v*>(&sh[(size_t)(nb + k) * 64 + (c - 64)]);
      else              v = *reinterpret_cast<const half4v*>(&h2[(size_t)(nb + k) * 128 + (c - 128)]);
#pragma unroll
      for (int j = 0; j < 4; j++) YsT[c + j][k] = v[j];
    }
    __syncthreads();
    half8v af = *reinterpret_cast<const half8v*>(&XsT[mtile * 16 + l16][kt * 32 + quad * 8]);
#pragma unroll
    for (int nt = 0; nt < 8; nt++) {
      half8v bf = *reinterpret_cast<const half8v*>(&YsT[(nhalf * 8 + nt) * 16 + l16][quad * 8]);
      acc[nt] = __builtin_amdgcn_mfma_f32_16x16x32_f16(af, bf, acc[nt], 0, 0, 0);
    }
  }
  float* dst = pF + (size_t)blockIdx.x * 16384;
#pragma unroll
  for (int nt = 0; nt < 8; nt++) {
#pragma unroll
    for (int r = 0; r < 4; r++) {
      dst[(mtile * 16 + quad * 4 + r) * 256 + (nhalf * 8 + nt) * 16 + l16] = acc[nt][r];
    }
  }
}

// ---------------- merge 32 partials/graph (XCD-swizzled) -> oadj, ssb, outp16 ----------------
__global__ __launch_bounds__(256) void merge_kernel(const float* __restrict__ pF, float* __restrict__ oadj,
                                                    float* __restrict__ ssb, _Float16* __restrict__ outp16) {
  int g = blockIdx.x & 7;
  int o4 = (blockIdx.x >> 3) * 256 + threadIdx.x;
  float sx = 0.f, sy = 0.f, sz = 0.f, sw = 0.f;
#pragma unroll
  for (int q = 0; q < 32; ++q) {
    float4 v = *reinterpret_cast<const float4*>(pF + (size_t)(q * 8 + g) * 16384 + o4 * 4);
    sx += v.x; sy += v.y; sz += v.z; sw += v.w;
  }
  int row = o4 >> 6;
  int c = (o4 & 63) * 4;
  if (c < 64) {
    float4 o = {sx, sy, sz, sw};
    *reinterpret_cast<float4*>(&oadj[g * 4096 + row * 64 + c]) = o;
  } else if (c < 128) {
    float4 o = {sx, sy, sz, sw};
    *reinterpret_cast<float4*>(&ssb[g * 4096 + row * 64 + (c - 64)]) = o;
  } else {
    half4v h = {(_Float16)sx, (_Float16)sy, (_Float16)sz, (_Float16)sw};
    *reinterpret_cast<half4v*>(&outp16[g * 8192 + row * 128 + (c - 128)]) = h;
  }
}

// ---------------- epilogue2: losses + adj-norm + pooled MFMA GEMM (8 blocks) ----------------
__global__ __launch_bounds__(256) void epilogue2_kernel(const float* __restrict__ oadj, const float* __restrict__ ssb,
                                                        const _Float16* __restrict__ outp16, const _Float16* __restrict__ wto,
                                                        const float* __restrict__ bo, const float* __restrict__ dn,
                                                        float* __restrict__ out) {
  __shared__ _Float16 outpS[64][136];
  __shared__ _Float16 WoT[128][136];
  __shared__ float red[256];
  __shared__ float rowsum[64];
  __shared__ float dw[4], w1[4], w2[4], w3[4];
  const int g = blockIdx.x, t = threadIdx.x;

#pragma unroll
  for (int i = 0; i < 8; i++) {
    int idx = i * 256 + t;
    int n = idx >> 4, k8 = (idx & 15) << 3;
    *reinterpret_cast<half8v*>(&WoT[n][k8]) = *reinterpret_cast<const half8v*>(&wto[n * 128 + k8]);
  }
#pragma unroll
  for (int i = 0; i < 4; i++) {
    int idx = i * 256 + t;
    int orow = idx >> 4, c8 = (idx & 15) * 8;
    half8v v = *reinterpret_cast<const half8v*>(&outp16[g * 8192 + orow * 128 + c8]);
    *reinterpret_cast<half8v*>(&outpS[orow][c8]) = v;
  }

  const int row = t >> 2, p = t & 3;
  float Areg[16];
  float trs_p = 0.f, ssq_p = 0.f;
#pragma unroll
  for (int c4 = 0; c4 < 4; c4++) {
    float4 a = *reinterpret_cast<const float4*>(&oadj[g * 4096 + row * 64 + p * 16 + c4 * 4]);
    Areg[c4 * 4 + 0] = a.x; Areg[c4 * 4 + 1] = a.y; Areg[c4 * 4 + 2] = a.z; Areg[c4 * 4 + 3] = a.w;
    float4 s = *reinterpret_cast<const float4*>(&ssb[g * 4096 + row * 64 + p * 16 + c4 * 4]);
    float vv[4] = {s.x, s.y, s.z, s.w};
#pragma unroll
    for (int jj = 0; jj < 4; jj++) {
      ssq_p += vv[jj] * vv[jj];
      int col = p * 16 + c4 * 4 + jj;
      if (col == row) trs_p += vv[jj];
    }
  }
  float da = 0.f;
#pragma unroll
  for (int i = 0; i < 16; i++) da += dn[g * 4096 + i * 256 + t];
  float dws = wave_sum(da);
  if ((t & 63) == 0) dw[t >> 6] = dws;

  float rs = 0.f, tra = 0.f;
#pragma unroll
  for (int c = 0; c < 16; c++) {
    int j = p * 16 + c;
    if (j == row) tra += Areg[c];
    else rs += Areg[c];
  }
  red[t] = rs;
  __syncthreads();
  if (p == 0) rowsum[row] = red[t] + red[t + 1] + red[t + 2] + red[t + 3];
  float v1 = wave_sum(tra), v2 = wave_sum(trs_p), v3 = wave_sum(ssq_p);
  if ((t & 63) == 0) { int w = t >> 6; w1[w] = v1; w2[w] = v2; w3[w] = v3; }
  __syncthreads();
  if (t == 0) {
    float TRA = w1[0] + w1[1] + w1[2] + w1[3];
    float TRS = w2[0] + w2[1] + w2[2] + w2[3];
    float SSQ = w3[0] + w3[1] + w3[2] + w3[3];
    float DEN = dw[0] + dw[1] + dw[2] + dw[3];
    atomicAdd(&out[98816], -(TRA / DEN) * 0.125f);
    float ssn = sqrtf(SSQ);
    atomicAdd(&out[98817], sqrtf(2.0f - TRS / (4.0f * ssn)) * 0.125f);
  }
  float di = sqrtf(rowsum[row]) + 1e-15f;
#pragma unroll
  for (int c = 0; c < 16; c++) {
    int j = p * 16 + c;
    float v = (j == row) ? 0.f : Areg[c];
    float dj = sqrtf(rowsum[j]) + 1e-15f;
    out[65536 + g * 4096 + row * 64 + j] = v / (di * dj);
  }
  if (t < 64) out[98304 + g * 64 + t] = (float)g;

  const int lane = t & 63;
  const int quad = lane >> 4, l16 = lane & 15;
  const int w = t >> 6;
  floatx4 acc[8];
#pragma unroll
  for (int ct = 0; ct < 8; ct++) acc[ct] = {0.f, 0.f, 0.f, 0.f};
#pragma unroll
  for (int kt = 0; kt < 4; kt++) {
    half8v af = *reinterpret_cast<const half8v*>(&outpS[w * 16 + l16][kt * 32 + quad * 8]);
#pragma unroll
    for (int ct = 0; ct < 8; ct++) {
      half8v bf = *reinterpret_cast<const half8v*>(&WoT[ct * 16 + l16][kt * 32 + quad * 8]);
      acc[ct] = __builtin_amdgcn_mfma_f32_16x16x32_f16(af, bf, acc[ct], 0, 0, 0);
    }
  }
#pragma unroll
  for (int r = 0; r < 4; r++) {
    int orow = w * 16 + quad * 4 + r;
#pragma unroll
    for (int ct = 0; ct < 8; ct++) {
      int col = ct * 16 + l16;
      float v = fmaxf(acc[ct][r] + bo[col], 0.f);
      out[(g * 64 + orow) * 128 + col] = v;
    }
  }
}

extern "C" void kernel_launch(void* const* d_in, const int* in_sizes, int n_in,
                              void* d_out, int out_size, void* d_ws, size_t ws_size,
                              hipStream_t stream) {
  const float* x   = (const float*)d_in[0];
  const int*   ei  = (const int*)d_in[1];
  const float* W1  = (const float*)d_in[3];
  const float* b1  = (const float*)d_in[4];
  const float* W2  = (const float*)d_in[5];
  const float* b2  = (const float*)d_in[6];
  const float* Wa1 = (const float*)d_in[7];
  const float* ba1 = (const float*)d_in[8];
  const float* Wa2 = (const float*)d_in[9];
  const float* ba2 = (const float*)d_in[10];
  const float* Wo  = (const float*)d_in[11];
  const float* bo  = (const float*)d_in[12];
  const int* src = ei;
  const int* dst = ei + NEDGES;
  float* out = (float*)d_out;

  char* ws = (char*)d_ws;
  size_t o = 0;
  auto alloc = [&](size_t bytes) -> void* {
    void* p = ws + o;
    o += (bytes + 255) & ~(size_t)255;
    return p;
  };
  _Float16* h16A = (_Float16*)alloc((size_t)NNODES * 128 * 2);
  _Float16* h16B = (_Float16*)alloc((size_t)NNODES * 128 * 2);
  _Float16* h16C = (_Float16*)alloc((size_t)NNODES * 128 * 2);
  _Float16* sh   = (_Float16*)alloc((size_t)NNODES * 64 * 2);
  _Float16* Gh   = (_Float16*)alloc((size_t)NNODES * 64 * 2);
  float* pF    = (float*)alloc((size_t)256 * 16384 * 4);
  float* dis   = (float*)alloc((size_t)NNODES * 4);
  int* offs    = (int*)alloc((size_t)(NNODES + 1) * 4);
  int* ssrc    = (int*)alloc((size_t)NEDGES * 4);
  int* pIn     = (int*)alloc((size_t)8 * CPG * 4096 * 4);
  int* cbase   = (int*)alloc((size_t)8 * CPG * 4096 * 4);
  float* dn    = (float*)alloc((size_t)NNODES * 4);
  float* oadj  = (float*)alloc(8 * 4096 * 4);
  float* ssb   = (float*)alloc(8 * 4096 * 4);
  _Float16* outp16 = (_Float16*)alloc(8 * 8192 * 2);
  _Float16* wt16   = (_Float16*)alloc((size_t)WT_TOTAL * 2);

  hipMemsetAsync(out + 98816, 0, 2 * sizeof(float), stream);

  hist2_kernel<<<8 * CPG, 256, 0, stream>>>(src, dst, pIn, W1, W2, Wa1, Wa2, Wo, wt16);
  scan2_kernel<<<8, 1024, 0, stream>>>(pIn, offs, cbase, dis);
  scatter2_kernel<<<8 * CPG, 256, 0, stream>>>(src, dst, cbase, ssrc);

  mgemm_kernel<0, 0, 1, 1><<<NNODES / 128, 256, 0, stream>>>(x, wt16 + WT1_OFF, nullptr, dis, h16A);
  aggregate_kernel<<<NNODES / 4, 256, 0, stream>>>(h16A, dis, offs, ssrc, b1, h16B, 1);
  mgemm_kernel<0, 0, 1, 0><<<NNODES / 128, 256, 0, stream>>>(h16B, wt16 + WT2_OFF, nullptr, dis, h16A);
  aggregate_kernel<<<NNODES / 4, 256, 0, stream>>>(h16A, dis, offs, ssrc, b2, h16C, 0);

  mlp_kernel<<<NNODES / 64, 256, 0, stream>>>(h16C, wt16 + WTA1_OFF, wt16 + WTA2_OFF, ba1, ba2, sh);

  gather_kernel<<<NNODES / 4, 256, 0, stream>>>(sh, offs, ssrc, Gh, dn);
  atb_kernel<<<256, 512, 0, stream>>>(sh, Gh, h16C, pF);
  merge_kernel<<<128, 256, 0, stream>>>(pF, oadj, ssb, outp16);
  epilogue2_kernel<<<8, 256, 0, stream>>>(oadj, ssb, outp16, wt16 + WTO_OFF, bo, dn, out);
}